// Round 5
// baseline (349.631 us; speedup 1.0000x reference)
//
#include <hip/hip_runtime.h>
#include <hip/hip_bf16.h>

// RSFConv2d round 5: 32x32x16 MFMA implicit GEMM.
//  vs R4: (1) bijective LDS swizzle slot16 = 4*(px&1) + (((px>>1)&3)^c)
//         -> all 8 16B bank-phases covered by any 8 consecutive px
//         (R4's swizzle only covered 4 -> 2-way conflict, 1.5e7 cycles);
//         (2) two-phase rolling stage: stage rows 0-9 | compute rows 0-7
//         while staging rows 10-17 | compute rows 8-15 (halves the
//         stage->barrier convoy, overlaps loads with MFMA);
//         (3) v_cvt_pk_bf16_f32 via __float22bfloat162_rn for staging.

typedef __attribute__((ext_vector_type(8))) short bf16x8;
typedef __attribute__((ext_vector_type(16))) float f32x16;
typedef __attribute__((ext_vector_type(4))) unsigned int u32x4;

__device__ __forceinline__ unsigned short f2bf(float f) {
    unsigned u = __float_as_uint(f);
    u = u + 0x7fffu + ((u >> 16) & 1u);  // RNE
    return (unsigned short)(u >> 16);
}
__device__ __forceinline__ float bf2f(unsigned short b) {
    return __uint_as_float(((unsigned)b) << 16);
}

// ---------------- kernel synthesis: one thread per (o,i) pair ----------------
__global__ __launch_bounds__(256) void prep_kernel(const float* __restrict__ fw,
                                                   unsigned short* __restrict__ wbuf)
{
    int gid = blockIdx.x * blockDim.x + threadIdx.x;
    if (gid >= 32 * 32) return;
    int o = gid >> 5;
    int i = gid & 31;

    const float* f = fw + (size_t)gid * 12;
    float re[3][2], im[3][2];
#pragma unroll
    for (int ky = 0; ky < 3; ++ky)
#pragma unroll
        for (int kx = 0; kx < 2; ++kx) {
            re[ky][kx] = f[(ky * 2 + kx) * 2 + 0];
            im[ky][kx] = f[(ky * 2 + kx) * 2 + 1];
        }

    const float c3[3] = {1.f, -0.5f, -0.5f};
    const float s3[3] = {0.f, 0.86602540378443864676f, -0.86602540378443864676f};

    float base[3][3];
#pragma unroll
    for (int y = 0; y < 3; ++y)
#pragma unroll
        for (int x = 0; x < 3; ++x) {
            float sum = 0.f;
#pragma unroll
            for (int ky = 0; ky < 3; ++ky)
#pragma unroll
                for (int kx = 0; kx < 3; ++kx) {
                    float rf, mf;
                    if (kx < 2) {
                        rf = re[ky][kx];
                        mf = im[ky][kx];
                    } else {
                        int kys = (3 - ky) % 3;
                        rf = re[kys][1];
                        mf = -im[kys][1];
                    }
                    int m = (ky * y + kx * x) % 3;
                    sum += rf * c3[m] - mf * s3[m];
                }
            base[y][x] = sum * (1.f / 9.f);
        }

    const float scales[4] = {1.f, 1.25f, 1.5625f, 1.953125f};
    const float coords[3] = {-2.f / 3.f, 0.f, 2.f / 3.f};

    float acc[3][3] = {{0.f, 0.f, 0.f}, {0.f, 0.f, 0.f}, {0.f, 0.f, 0.f}};

    for (int t = 0; t < 32; ++t) {
        int r = t >> 2, si = t & 3;
        float th = (float)r * 0.78539816339744830961f;
        float sc = scales[si];
        float c = cosf(th) * sc;
        float s = sinf(th) * sc;
#pragma unroll
        for (int p = 0; p < 3; ++p) {
#pragma unroll
            for (int q = 0; q < 3; ++q) {
                float gxo = coords[q], gyo = coords[p];
                float gx = c * gxo - s * gyo;
                float gy = s * gxo + c * gyo;
                float ix = ((gx + 1.f) * 3.f - 1.f) * 0.5f;
                float iy = ((gy + 1.f) * 3.f - 1.f) * 0.5f;
                float fx0 = floorf(ix), fy0 = floorf(iy);
                int x0 = (int)fx0, y0 = (int)fy0;
                int x1 = x0 + 1, y1 = y0 + 1;
                float wx1 = ix - fx0, wy1 = iy - fy0;
                float wx0 = 1.f - wx1, wy0 = 1.f - wy1;

                float v = 0.f;
                {
                    int yc = min(max(y0, 0), 2), xc = min(max(x0, 0), 2);
                    bool ok = (x0 >= 0) & (x0 < 3) & (y0 >= 0) & (y0 < 3);
                    v += (ok ? base[yc][xc] : 0.f) * (wy0 * wx0);
                }
                {
                    int yc = min(max(y0, 0), 2), xc = min(max(x1, 0), 2);
                    bool ok = (x1 >= 0) & (x1 < 3) & (y0 >= 0) & (y0 < 3);
                    v += (ok ? base[yc][xc] : 0.f) * (wy0 * wx1);
                }
                {
                    int yc = min(max(y1, 0), 2), xc = min(max(x0, 0), 2);
                    bool ok = (x0 >= 0) & (x0 < 3) & (y1 >= 0) & (y1 < 3);
                    v += (ok ? base[yc][xc] : 0.f) * (wy1 * wx0);
                }
                {
                    int yc = min(max(y1, 0), 2), xc = min(max(x1, 0), 2);
                    bool ok = (x1 >= 0) & (x1 < 3) & (y1 >= 0) & (y1 < 3);
                    v += (ok ? base[yc][xc] : 0.f) * (wy1 * wx1);
                }
                acc[p][q] += v;
            }
        }
    }

    // wbuf[(tap*2+hl)*1024 + o*32 + i]
#pragma unroll
    for (int p = 0; p < 3; ++p)
#pragma unroll
        for (int q = 0; q < 3; ++q) {
            int t = p * 3 + q;
            float w = acc[p][q] * (1.f / 32.f);
            unsigned short wh = f2bf(w);
            unsigned short wl = f2bf(w - bf2f(wh));
            size_t b = (size_t)(t * 2) * 1024 + o * 32 + i;
            wbuf[b] = wh;
            wbuf[b + 1024] = wl;
        }
}

// ---------------- conv ----------------
#define TLW 32
#define TLH 16
#define LCOLS 34
#define LROWS 18

// bijective bank swizzle: any 8 consecutive px cover all 8 16B phases
__device__ __forceinline__ unsigned lds_byte(int px, int c) {
    return ((unsigned)px << 6) + ((((unsigned)(px >> 1) & 3u) ^ (unsigned)c) << 4);
}

template <int NROWS>
__device__ __forceinline__ void stage_rows(unsigned* slds, const float* xn,
                                           int x0t, int y0t, int r0, int tid)
{
    constexpr int NU = NROWS * LCOLS * 4;
    for (int t = tid; t < NU; t += 512) {
        int c = t / (NROWS * LCOLS);
        int rem = t - c * (NROWS * LCOLS);
        int row = rem / LCOLS;
        int col = rem - row * LCOLS;
        int gy = y0t + r0 + row - 1;
        int gx = x0t + col - 1;
        bool ok = ((unsigned)gy < 512u) & ((unsigned)gx < 512u);
        const float* src = xn + (((size_t)c << 3) << 18) + ((gy << 9) + gx);
        u32x4 d;
#pragma unroll
        for (int j = 0; j < 4; ++j) {
            float v0 = ok ? src[(size_t)(2 * j) << 18] : 0.f;
            float v1 = ok ? src[(size_t)(2 * j + 1) << 18] : 0.f;
            __hip_bfloat162 h2 = __float22bfloat162_rn(make_float2(v0, v1));
            unsigned u;
            __builtin_memcpy(&u, &h2, 4);
            d[j] = u;
        }
        int px = (r0 + row) * LCOLS + col;
        *(u32x4*)((char*)slds + lds_byte(px, c)) = d;
    }
}

__device__ __forceinline__ f32x16 compute_row(const unsigned* slds,
                                              const unsigned short* __restrict__ wbuf,
                                              int lrow0, int pxl, int kh)
{
    f32x16 acc;
#pragma unroll
    for (int r = 0; r < 16; ++r) acc[r] = 0.f;

#pragma unroll
    for (int dy = 0; dy < 3; ++dy) {
        bf16x8 A[3][2][2];  // [dx][hl][ks]
#pragma unroll
        for (int dx = 0; dx < 3; ++dx)
#pragma unroll
            for (int hl = 0; hl < 2; ++hl)
#pragma unroll
                for (int ks = 0; ks < 2; ++ks) {
                    int tap = dy * 3 + dx;
                    A[dx][hl][ks] = *(const bf16x8*)(wbuf + (size_t)(tap * 2 + hl) * 1024 +
                                                     pxl * 32 + ks * 16 + kh * 8);
                }
        int lrow = lrow0 + dy;
#pragma unroll
        for (int dx = 0; dx < 3; ++dx) {
            int px = lrow * LCOLS + dx + pxl;
#pragma unroll
            for (int ks = 0; ks < 2; ++ks) {
                bf16x8 b = *(const bf16x8*)((const char*)slds + lds_byte(px, ks * 2 + kh));
                acc = __builtin_amdgcn_mfma_f32_32x32x16_bf16(A[dx][0][ks], b, acc, 0, 0, 0);
                acc = __builtin_amdgcn_mfma_f32_32x32x16_bf16(A[dx][1][ks], b, acc, 0, 0, 0);
            }
        }
    }
    return acc;
}

__device__ __forceinline__ void store_row(float* __restrict__ out, f32x16 acc,
                                          int n, int gy, int gx0, int kh)
{
#pragma unroll
    for (int reg = 0; reg < 16; ++reg) {
        int o = (reg & 3) + 8 * (reg >> 2) + 4 * kh;
        size_t idx = ((size_t)(n * 32 + o) << 18) + (size_t)(gy << 9) + gx0;
        __builtin_nontemporal_store(acc[reg], &out[idx]);
    }
}

__global__ __launch_bounds__(512, 4) void conv_mfma(const float* __restrict__ x,
                                                    const unsigned short* __restrict__ wbuf,
                                                    float* __restrict__ out)
{
    __shared__ unsigned slds[LROWS * LCOLS * 16];  // 18*34*64 B = 39168 B

    const int x0t = blockIdx.x * TLW;
    const int y0t = blockIdx.y * TLH;
    const int n = blockIdx.z;
    const int tid = threadIdx.x;
    const float* xn = x + ((size_t)n << 23);

    const int lane = tid & 63;
    const int wv = tid >> 6;
    const int pxl = lane & 31;
    const int kh = lane >> 5;

    // phase -1: stage rows 0..9 (top halo + first 8+1 rows)
    stage_rows<10>(slds, xn, x0t, y0t, 0, tid);
    __syncthreads();

    // phase 0: compute out rows 0..7 while staging rows 10..17 (disjoint LDS)
    f32x16 a0 = compute_row(slds, wbuf, wv, pxl, kh);
    stage_rows<8>(slds, xn, x0t, y0t, 10, tid);
    store_row(out, a0, n, y0t + wv, x0t + pxl, kh);
    __syncthreads();

    // phase 1: compute out rows 8..15
    f32x16 a1 = compute_row(slds, wbuf, 8 + wv, pxl, kh);
    store_row(out, a1, n, y0t + 8 + wv, x0t + pxl, kh);
}

extern "C" void kernel_launch(void* const* d_in, const int* in_sizes, int n_in,
                              void* d_out, int out_size, void* d_ws, size_t ws_size,
                              hipStream_t stream) {
    const float* x = (const float*)d_in[0];
    const float* fw = (const float*)d_in[1];
    float* out = (float*)d_out;
    unsigned short* wbuf = (unsigned short*)d_ws;  // 18*1024 bf16 = 36864 B

    prep_kernel<<<dim3(4), 256, 0, stream>>>(fw, wbuf);
    conv_mfma<<<dim3(512 / TLW, 512 / TLH, 8), 512, 0, stream>>>(x, wbuf, out);
}

// Round 6
// 275.807 us; speedup vs baseline: 1.2677x; 1.2677x over previous
//
#include <hip/hip_runtime.h>
#include <hip/hip_bf16.h>

// RSFConv2d round 6: 32x32x16 MFMA implicit GEMM.
//  = R4 structure (single stage -> barrier -> fat compute, A-frags loaded once
//    per dy and shared across both output rows) which ran 202us, plus:
//  - bijective LDS swizzle slot16 = 4*(px&1) + (((px>>1)&3)^c): any 8
//    consecutive px cover all 8 16B bank phases (R4's swizzle repeated phases
//    with period 4 -> 2-way conflict on EVERY LDS access, 1.5e7 cycles).
//  - packed bf16 conversion via __float22bfloat162_rn (v_cvt_pk_bf16_f32).
//  R5's two-phase split REGRESSED (422us): it doubled per-phase A-fragment
//  global loads and exposed their L2 latency -> do not split the compute.

typedef __attribute__((ext_vector_type(8))) short bf16x8;
typedef __attribute__((ext_vector_type(16))) float f32x16;
typedef __attribute__((ext_vector_type(4))) unsigned int u32x4;

__device__ __forceinline__ unsigned short f2bf(float f) {
    unsigned u = __float_as_uint(f);
    u = u + 0x7fffu + ((u >> 16) & 1u);  // RNE
    return (unsigned short)(u >> 16);
}
__device__ __forceinline__ float bf2f(unsigned short b) {
    return __uint_as_float(((unsigned)b) << 16);
}

// ---------------- kernel synthesis: one thread per (o,i) pair ----------------
__global__ __launch_bounds__(256) void prep_kernel(const float* __restrict__ fw,
                                                   unsigned short* __restrict__ wbuf)
{
    int gid = blockIdx.x * blockDim.x + threadIdx.x;
    if (gid >= 32 * 32) return;
    int o = gid >> 5;
    int i = gid & 31;

    const float* f = fw + (size_t)gid * 12;
    float re[3][2], im[3][2];
#pragma unroll
    for (int ky = 0; ky < 3; ++ky)
#pragma unroll
        for (int kx = 0; kx < 2; ++kx) {
            re[ky][kx] = f[(ky * 2 + kx) * 2 + 0];
            im[ky][kx] = f[(ky * 2 + kx) * 2 + 1];
        }

    const float c3[3] = {1.f, -0.5f, -0.5f};
    const float s3[3] = {0.f, 0.86602540378443864676f, -0.86602540378443864676f};

    float base[3][3];
#pragma unroll
    for (int y = 0; y < 3; ++y)
#pragma unroll
        for (int x = 0; x < 3; ++x) {
            float sum = 0.f;
#pragma unroll
            for (int ky = 0; ky < 3; ++ky)
#pragma unroll
                for (int kx = 0; kx < 3; ++kx) {
                    float rf, mf;
                    if (kx < 2) {
                        rf = re[ky][kx];
                        mf = im[ky][kx];
                    } else {
                        int kys = (3 - ky) % 3;
                        rf = re[kys][1];
                        mf = -im[kys][1];
                    }
                    int m = (ky * y + kx * x) % 3;
                    sum += rf * c3[m] - mf * s3[m];
                }
            base[y][x] = sum * (1.f / 9.f);
        }

    const float scales[4] = {1.f, 1.25f, 1.5625f, 1.953125f};
    const float coords[3] = {-2.f / 3.f, 0.f, 2.f / 3.f};

    float acc[3][3] = {{0.f, 0.f, 0.f}, {0.f, 0.f, 0.f}, {0.f, 0.f, 0.f}};

    for (int t = 0; t < 32; ++t) {
        int r = t >> 2, si = t & 3;
        float th = (float)r * 0.78539816339744830961f;
        float sc = scales[si];
        float c = cosf(th) * sc;
        float s = sinf(th) * sc;
#pragma unroll
        for (int p = 0; p < 3; ++p) {
#pragma unroll
            for (int q = 0; q < 3; ++q) {
                float gxo = coords[q], gyo = coords[p];
                float gx = c * gxo - s * gyo;
                float gy = s * gxo + c * gyo;
                float ix = ((gx + 1.f) * 3.f - 1.f) * 0.5f;
                float iy = ((gy + 1.f) * 3.f - 1.f) * 0.5f;
                float fx0 = floorf(ix), fy0 = floorf(iy);
                int x0 = (int)fx0, y0 = (int)fy0;
                int x1 = x0 + 1, y1 = y0 + 1;
                float wx1 = ix - fx0, wy1 = iy - fy0;
                float wx0 = 1.f - wx1, wy0 = 1.f - wy1;

                float v = 0.f;
                {
                    int yc = min(max(y0, 0), 2), xc = min(max(x0, 0), 2);
                    bool ok = (x0 >= 0) & (x0 < 3) & (y0 >= 0) & (y0 < 3);
                    v += (ok ? base[yc][xc] : 0.f) * (wy0 * wx0);
                }
                {
                    int yc = min(max(y0, 0), 2), xc = min(max(x1, 0), 2);
                    bool ok = (x1 >= 0) & (x1 < 3) & (y0 >= 0) & (y0 < 3);
                    v += (ok ? base[yc][xc] : 0.f) * (wy0 * wx1);
                }
                {
                    int yc = min(max(y1, 0), 2), xc = min(max(x0, 0), 2);
                    bool ok = (x0 >= 0) & (x0 < 3) & (y1 >= 0) & (y1 < 3);
                    v += (ok ? base[yc][xc] : 0.f) * (wy1 * wx0);
                }
                {
                    int yc = min(max(y1, 0), 2), xc = min(max(x1, 0), 2);
                    bool ok = (x1 >= 0) & (x1 < 3) & (y1 >= 0) & (y1 < 3);
                    v += (ok ? base[yc][xc] : 0.f) * (wy1 * wx1);
                }
                acc[p][q] += v;
            }
        }
    }

    // wbuf[(tap*2+hl)*1024 + o*32 + i]: A rows = o, k = i.
#pragma unroll
    for (int p = 0; p < 3; ++p)
#pragma unroll
        for (int q = 0; q < 3; ++q) {
            int t = p * 3 + q;
            float w = acc[p][q] * (1.f / 32.f);
            unsigned short wh = f2bf(w);
            unsigned short wl = f2bf(w - bf2f(wh));
            size_t b = (size_t)(t * 2) * 1024 + o * 32 + i;
            wbuf[b] = wh;
            wbuf[b + 1024] = wl;
        }
}

// ---------------- conv: 16x32 tile, 8 waves, 32x32x16 MFMA ----------------
#define TLH 16
#define TLW 32
#define LCOLS 34
#define NPX 612  // 18*34 halo pixels, 64 B each (32 ch bf16)

// bijective bank swizzle: any 8 consecutive px cover all 8 16B phases
__device__ __forceinline__ unsigned lds_byte(int px, int c) {
    return ((unsigned)px << 6) + ((((unsigned)(px >> 1) & 3u) ^ (unsigned)c) << 4);
}

__global__ __launch_bounds__(512, 4) void conv_mfma(const float* __restrict__ x,
                                                    const unsigned short* __restrict__ wbuf,
                                                    float* __restrict__ out)
{
    __shared__ unsigned slds[NPX * 16];  // 39168 B

    const int x0t = blockIdx.x * TLW;
    const int y0t = blockIdx.y * TLH;
    const int n = blockIdx.z;
    const int tid = threadIdx.x;
    const float* xn = x + ((size_t)n << 23);

    // ---- stage: pack channel-octet c of each px into 16 B, swizzled slot ----
    for (int t = tid; t < 4 * NPX; t += 512) {
        int c = t / NPX;             // channel octet 0..3 (ch 8c..8c+7)
        int px = t - c * NPX;
        int row = px / LCOLS;
        int col = px - row * LCOLS;
        int gy = y0t + row - 1;
        int gx = x0t + col - 1;
        bool ok = ((unsigned)gy < 512u) & ((unsigned)gx < 512u);
        const float* src = xn + (((size_t)c << 3) << 18) + ((gy << 9) + gx);
        u32x4 d;
#pragma unroll
        for (int j = 0; j < 4; ++j) {
            float v0 = ok ? src[(size_t)(2 * j) << 18] : 0.f;
            float v1 = ok ? src[(size_t)(2 * j + 1) << 18] : 0.f;
            __hip_bfloat162 h2 = __float22bfloat162_rn(make_float2(v0, v1));
            unsigned u;
            __builtin_memcpy(&u, &h2, 4);
            d[j] = u;
        }
        *(u32x4*)((char*)slds + lds_byte(px, c)) = d;
    }
    __syncthreads();

    // ---- MFMA: wave wv owns out rows {2wv, 2wv+1}, all 32 o ----
    const int lane = tid & 63;
    const int wv = tid >> 6;
    const int pxl = lane & 31;  // B col = pixel
    const int kh = lane >> 5;   // B k-half
    const int r0 = wv << 1;

    f32x16 acc[2];
#pragma unroll
    for (int f = 0; f < 2; ++f)
#pragma unroll
        for (int r = 0; r < 16; ++r) acc[f][r] = 0.f;

#pragma unroll 1
    for (int dy = 0; dy < 3; ++dy) {
        // A-frags for this dy: lane holds row o=pxl, k = kh*8 + j of K=16
        bf16x8 A[3][2][2];  // [dx][hl][kstep]
#pragma unroll
        for (int dx = 0; dx < 3; ++dx)
#pragma unroll
            for (int hl = 0; hl < 2; ++hl)
#pragma unroll
                for (int ks = 0; ks < 2; ++ks) {
                    int tap = dy * 3 + dx;
                    A[dx][hl][ks] = *(const bf16x8*)(wbuf + (size_t)(tap * 2 + hl) * 1024 +
                                                     pxl * 32 + ks * 16 + kh * 8);
                }
#pragma unroll
        for (int f = 0; f < 2; ++f) {
            int lrow = r0 + f + dy;  // LDS row (0 = global y0t-1)
#pragma unroll
            for (int dx = 0; dx < 3; ++dx) {
                int px = lrow * LCOLS + dx + pxl;
#pragma unroll
                for (int ks = 0; ks < 2; ++ks) {
                    bf16x8 b = *(const bf16x8*)((const char*)slds + lds_byte(px, ks * 2 + kh));
                    acc[f] = __builtin_amdgcn_mfma_f32_32x32x16_bf16(A[dx][0][ks], b, acc[f], 0, 0, 0);
                    acc[f] = __builtin_amdgcn_mfma_f32_32x32x16_bf16(A[dx][1][ks], b, acc[f], 0, 0, 0);
                }
            }
        }
    }

    // ---- epilogue: C/D col=lane&31 (px), row=(reg&3)+8*(reg>>2)+4*(lane>>5) (o)
#pragma unroll
    for (int f = 0; f < 2; ++f) {
        int gy = y0t + r0 + f;
#pragma unroll
        for (int reg = 0; reg < 16; ++reg) {
            int o = (reg & 3) + 8 * (reg >> 2) + 4 * kh;
            size_t idx = ((size_t)(n * 32 + o) << 18) + (size_t)(gy << 9) + x0t + pxl;
            __builtin_nontemporal_store(acc[f][reg], &out[idx]);
        }
    }
}

extern "C" void kernel_launch(void* const* d_in, const int* in_sizes, int n_in,
                              void* d_out, int out_size, void* d_ws, size_t ws_size,
                              hipStream_t stream) {
    const float* x = (const float*)d_in[0];
    const float* fw = (const float*)d_in[1];
    float* out = (float*)d_out;
    unsigned short* wbuf = (unsigned short*)d_ws;  // 18*1024 bf16 = 36864 B

    prep_kernel<<<dim3(4), 256, 0, stream>>>(fw, wbuf);
    conv_mfma<<<dim3(512 / TLW, 512 / TLH, 8), 512, 0, stream>>>(x, wbuf, out);
}

// Round 7
// 242.581 us; speedup vs baseline: 1.4413x; 1.1370x over previous
//
#include <hip/hip_runtime.h>
#include <hip/hip_bf16.h>

// RSFConv2d round 7: 32x32x16 MFMA implicit GEMM.
//  vs R6: staging vectorized along x — unit = (ch-octet, row, x-quad):
//  8x global_load_dwordx4 (4 px of one channel each, 16B aligned) ->
//  register transpose -> 4x ds_write_b128. VMEM insts/block 19584 -> ~5760.
//  Halo columns (gx = x0t-1, x0t+32) via 144 scalar units.
//  Conversion reverted to R4's manual f2bf. Read swizzle = R6 (conflict-free
//  reads; residual counter is write-side, ~0.4us/block, accepted).
//  Compute/epilogue identical to R4/R6 (202us structure).

typedef __attribute__((ext_vector_type(8))) short bf16x8;
typedef __attribute__((ext_vector_type(16))) float f32x16;
typedef __attribute__((ext_vector_type(4))) unsigned int u32x4;
typedef __attribute__((ext_vector_type(4))) float f32x4v;

__device__ __forceinline__ unsigned short f2bf(float f) {
    unsigned u = __float_as_uint(f);
    u = u + 0x7fffu + ((u >> 16) & 1u);  // RNE
    return (unsigned short)(u >> 16);
}
__device__ __forceinline__ float bf2f(unsigned short b) {
    return __uint_as_float(((unsigned)b) << 16);
}

// ---------------- kernel synthesis: one thread per (o,i) pair ----------------
__global__ __launch_bounds__(256) void prep_kernel(const float* __restrict__ fw,
                                                   unsigned short* __restrict__ wbuf)
{
    int gid = blockIdx.x * blockDim.x + threadIdx.x;
    if (gid >= 32 * 32) return;
    int o = gid >> 5;
    int i = gid & 31;

    const float* f = fw + (size_t)gid * 12;
    float re[3][2], im[3][2];
#pragma unroll
    for (int ky = 0; ky < 3; ++ky)
#pragma unroll
        for (int kx = 0; kx < 2; ++kx) {
            re[ky][kx] = f[(ky * 2 + kx) * 2 + 0];
            im[ky][kx] = f[(ky * 2 + kx) * 2 + 1];
        }

    const float c3[3] = {1.f, -0.5f, -0.5f};
    const float s3[3] = {0.f, 0.86602540378443864676f, -0.86602540378443864676f};

    float base[3][3];
#pragma unroll
    for (int y = 0; y < 3; ++y)
#pragma unroll
        for (int x = 0; x < 3; ++x) {
            float sum = 0.f;
#pragma unroll
            for (int ky = 0; ky < 3; ++ky)
#pragma unroll
                for (int kx = 0; kx < 3; ++kx) {
                    float rf, mf;
                    if (kx < 2) {
                        rf = re[ky][kx];
                        mf = im[ky][kx];
                    } else {
                        int kys = (3 - ky) % 3;
                        rf = re[kys][1];
                        mf = -im[kys][1];
                    }
                    int m = (ky * y + kx * x) % 3;
                    sum += rf * c3[m] - mf * s3[m];
                }
            base[y][x] = sum * (1.f / 9.f);
        }

    const float scales[4] = {1.f, 1.25f, 1.5625f, 1.953125f};
    const float coords[3] = {-2.f / 3.f, 0.f, 2.f / 3.f};

    float acc[3][3] = {{0.f, 0.f, 0.f}, {0.f, 0.f, 0.f}, {0.f, 0.f, 0.f}};

    for (int t = 0; t < 32; ++t) {
        int r = t >> 2, si = t & 3;
        float th = (float)r * 0.78539816339744830961f;
        float sc = scales[si];
        float c = cosf(th) * sc;
        float s = sinf(th) * sc;
#pragma unroll
        for (int p = 0; p < 3; ++p) {
#pragma unroll
            for (int q = 0; q < 3; ++q) {
                float gxo = coords[q], gyo = coords[p];
                float gx = c * gxo - s * gyo;
                float gy = s * gxo + c * gyo;
                float ix = ((gx + 1.f) * 3.f - 1.f) * 0.5f;
                float iy = ((gy + 1.f) * 3.f - 1.f) * 0.5f;
                float fx0 = floorf(ix), fy0 = floorf(iy);
                int x0 = (int)fx0, y0 = (int)fy0;
                int x1 = x0 + 1, y1 = y0 + 1;
                float wx1 = ix - fx0, wy1 = iy - fy0;
                float wx0 = 1.f - wx1, wy0 = 1.f - wy1;

                float v = 0.f;
                {
                    int yc = min(max(y0, 0), 2), xc = min(max(x0, 0), 2);
                    bool ok = (x0 >= 0) & (x0 < 3) & (y0 >= 0) & (y0 < 3);
                    v += (ok ? base[yc][xc] : 0.f) * (wy0 * wx0);
                }
                {
                    int yc = min(max(y0, 0), 2), xc = min(max(x1, 0), 2);
                    bool ok = (x1 >= 0) & (x1 < 3) & (y0 >= 0) & (y0 < 3);
                    v += (ok ? base[yc][xc] : 0.f) * (wy0 * wx1);
                }
                {
                    int yc = min(max(y1, 0), 2), xc = min(max(x0, 0), 2);
                    bool ok = (x0 >= 0) & (x0 < 3) & (y1 >= 0) & (y1 < 3);
                    v += (ok ? base[yc][xc] : 0.f) * (wy1 * wx0);
                }
                {
                    int yc = min(max(y1, 0), 2), xc = min(max(x1, 0), 2);
                    bool ok = (x1 >= 0) & (x1 < 3) & (y1 >= 0) & (y1 < 3);
                    v += (ok ? base[yc][xc] : 0.f) * (wy1 * wx1);
                }
                acc[p][q] += v;
            }
        }
    }

    // wbuf[(tap*2+hl)*1024 + o*32 + i]: A rows = o, k = i.
#pragma unroll
    for (int p = 0; p < 3; ++p)
#pragma unroll
        for (int q = 0; q < 3; ++q) {
            int t = p * 3 + q;
            float w = acc[p][q] * (1.f / 32.f);
            unsigned short wh = f2bf(w);
            unsigned short wl = f2bf(w - bf2f(wh));
            size_t b = (size_t)(t * 2) * 1024 + o * 32 + i;
            wbuf[b] = wh;
            wbuf[b + 1024] = wl;
        }
}

// ---------------- conv: 16x32 tile, 8 waves, 32x32x16 MFMA ----------------
#define TLH 16
#define TLW 32
#define LCOLS 34
#define NPX 612  // 18*34 halo pixels, 64 B each (32 ch bf16)

// read-conflict-free bank swizzle: any 8 consecutive px cover all 8 16B phases
__device__ __forceinline__ unsigned lds_byte(int px, int c) {
    return ((unsigned)px << 6) + ((((unsigned)(px >> 1) & 3u) ^ (unsigned)c) << 4);
}

__global__ __launch_bounds__(512, 4) void conv_mfma(const float* __restrict__ x,
                                                    const unsigned short* __restrict__ wbuf,
                                                    float* __restrict__ out)
{
    __shared__ unsigned slds[NPX * 16];  // 39168 B

    const int x0t = blockIdx.x * TLW;
    const int y0t = blockIdx.y * TLH;
    const int n = blockIdx.z;
    const int tid = threadIdx.x;
    const float* xn = x + ((size_t)n << 23);

    // ---- stage: vector units (c-octet, row, x-quad) + scalar halo columns ----
    // vector unit: 8x dwordx4 (4 px of one channel) -> transpose -> 4x b128
    for (int t = tid; t < 576 + 144; t += 512) {
        if (t < 576) {
            int c = t / 144;             // channel octet
            int rem = t - c * 144;
            int row = rem >> 3;
            int q = rem & 7;
            int gy = y0t + row - 1;
            int gx0 = x0t + (q << 2);    // 16B-aligned
            float v[8][4];
            if ((unsigned)gy < 512u) {
                const float* src = xn + (((size_t)c << 3) << 18) + ((gy << 9) + gx0);
#pragma unroll
                for (int cc = 0; cc < 8; ++cc) {
                    f32x4v ld = *(const f32x4v*)(src + ((size_t)cc << 18));
#pragma unroll
                    for (int j = 0; j < 4; ++j) v[cc][j] = ld[j];
                }
            } else {
#pragma unroll
                for (int cc = 0; cc < 8; ++cc)
#pragma unroll
                    for (int j = 0; j < 4; ++j) v[cc][j] = 0.f;
            }
            int px0 = row * LCOLS + 1 + (q << 2);
#pragma unroll
            for (int j = 0; j < 4; ++j) {
                u32x4 d;
#pragma unroll
                for (int p = 0; p < 4; ++p)
                    d[p] = (unsigned)f2bf(v[2 * p][j]) | ((unsigned)f2bf(v[2 * p + 1][j]) << 16);
                *(u32x4*)((char*)slds + lds_byte(px0 + j, c)) = d;
            }
        } else {
            int s = t - 576;
            int c = s / 36;
            int rem = s - c * 36;
            int row = rem >> 1;
            int side = rem & 1;
            int gy = y0t + row - 1;
            int gx = x0t + (side ? 32 : -1);
            bool ok = ((unsigned)gy < 512u) & ((unsigned)gx < 512u);
            u32x4 d;
#pragma unroll
            for (int p = 0; p < 4; ++p) {
                float f0 = 0.f, f1 = 0.f;
                if (ok) {
                    const float* srcp = xn + (((size_t)(c * 8 + 2 * p)) << 18) + ((gy << 9) + gx);
                    f0 = srcp[0];
                    f1 = srcp[(size_t)1 << 18];
                }
                d[p] = (unsigned)f2bf(f0) | ((unsigned)f2bf(f1) << 16);
            }
            int px = row * LCOLS + (side ? 33 : 0);
            *(u32x4*)((char*)slds + lds_byte(px, c)) = d;
        }
    }
    __syncthreads();

    // ---- MFMA: wave wv owns out rows {2wv, 2wv+1}, all 32 o ----
    const int lane = tid & 63;
    const int wv = tid >> 6;
    const int pxl = lane & 31;  // B col = pixel
    const int kh = lane >> 5;   // B k-half
    const int r0 = wv << 1;

    f32x16 acc[2];
#pragma unroll
    for (int f = 0; f < 2; ++f)
#pragma unroll
        for (int r = 0; r < 16; ++r) acc[f][r] = 0.f;

#pragma unroll 1
    for (int dy = 0; dy < 3; ++dy) {
        // A-frags for this dy: lane holds row o=pxl, k = kh*8 + j of K=16
        bf16x8 A[3][2][2];  // [dx][hl][kstep]
#pragma unroll
        for (int dx = 0; dx < 3; ++dx)
#pragma unroll
            for (int hl = 0; hl < 2; ++hl)
#pragma unroll
                for (int ks = 0; ks < 2; ++ks) {
                    int tap = dy * 3 + dx;
                    A[dx][hl][ks] = *(const bf16x8*)(wbuf + (size_t)(tap * 2 + hl) * 1024 +
                                                     pxl * 32 + ks * 16 + kh * 8);
                }
#pragma unroll
        for (int f = 0; f < 2; ++f) {
            int lrow = r0 + f + dy;  // LDS row (0 = global y0t-1)
#pragma unroll
            for (int dx = 0; dx < 3; ++dx) {
                int px = lrow * LCOLS + dx + pxl;
#pragma unroll
                for (int ks = 0; ks < 2; ++ks) {
                    bf16x8 b = *(const bf16x8*)((const char*)slds + lds_byte(px, ks * 2 + kh));
                    acc[f] = __builtin_amdgcn_mfma_f32_32x32x16_bf16(A[dx][0][ks], b, acc[f], 0, 0, 0);
                    acc[f] = __builtin_amdgcn_mfma_f32_32x32x16_bf16(A[dx][1][ks], b, acc[f], 0, 0, 0);
                }
            }
        }
    }

    // ---- epilogue: C/D col=lane&31 (px), row=(reg&3)+8*(reg>>2)+4*(lane>>5) (o)
#pragma unroll
    for (int f = 0; f < 2; ++f) {
        int gy = y0t + r0 + f;
#pragma unroll
        for (int reg = 0; reg < 16; ++reg) {
            int o = (reg & 3) + 8 * (reg >> 2) + 4 * kh;
            size_t idx = ((size_t)(n * 32 + o) << 18) + (size_t)(gy << 9) + x0t + pxl;
            __builtin_nontemporal_store(acc[f][reg], &out[idx]);
        }
    }
}

extern "C" void kernel_launch(void* const* d_in, const int* in_sizes, int n_in,
                              void* d_out, int out_size, void* d_ws, size_t ws_size,
                              hipStream_t stream) {
    const float* x = (const float*)d_in[0];
    const float* fw = (const float*)d_in[1];
    float* out = (float*)d_out;
    unsigned short* wbuf = (unsigned short*)d_ws;  // 18*1024 bf16 = 36864 B

    prep_kernel<<<dim3(4), 256, 0, stream>>>(fw, wbuf);
    conv_mfma<<<dim3(512 / TLW, 512 / TLH, 8), 512, 0, stream>>>(x, wbuf, out);
}

// Round 8
// 221.358 us; speedup vs baseline: 1.5795x; 1.0959x over previous
//
#include <hip/hip_runtime.h>
#include <hip/hip_bf16.h>

// RSFConv2d round 8: 32x32x16 MFMA implicit GEMM.
//  vs R7: (1) tile 16x32 -> 8x32, 256-thr blocks (4 waves x 2 rows):
//         LDS 39.4KB -> 21.8KB => 7 blocks/CU resident (was 2.4 avg) --
//         R7 post-mortem showed we're at 50% of BW-saturation purely from
//         too few in-flight stage convoys (all pipes <16% busy).
//         (2) bijective XCD swizzle on a flat 8192 grid, y-fastest within
//         XCD: each XCD owns exactly one batch image -> halo-row lines
//         (128B) reuse in-XCD L2 instead of cross-XCD refetch.
//  Stage (vectorized x-quad transpose), compute, epilogue = R7/R4 proven.

typedef __attribute__((ext_vector_type(8))) short bf16x8;
typedef __attribute__((ext_vector_type(16))) float f32x16;
typedef __attribute__((ext_vector_type(4))) unsigned int u32x4;
typedef __attribute__((ext_vector_type(4))) float f32x4v;

__device__ __forceinline__ unsigned short f2bf(float f) {
    unsigned u = __float_as_uint(f);
    u = u + 0x7fffu + ((u >> 16) & 1u);  // RNE
    return (unsigned short)(u >> 16);
}
__device__ __forceinline__ float bf2f(unsigned short b) {
    return __uint_as_float(((unsigned)b) << 16);
}

// ---------------- kernel synthesis: one thread per (o,i) pair ----------------
__global__ __launch_bounds__(256) void prep_kernel(const float* __restrict__ fw,
                                                   unsigned short* __restrict__ wbuf)
{
    int gid = blockIdx.x * blockDim.x + threadIdx.x;
    if (gid >= 32 * 32) return;
    int o = gid >> 5;
    int i = gid & 31;

    const float* f = fw + (size_t)gid * 12;
    float re[3][2], im[3][2];
#pragma unroll
    for (int ky = 0; ky < 3; ++ky)
#pragma unroll
        for (int kx = 0; kx < 2; ++kx) {
            re[ky][kx] = f[(ky * 2 + kx) * 2 + 0];
            im[ky][kx] = f[(ky * 2 + kx) * 2 + 1];
        }

    const float c3[3] = {1.f, -0.5f, -0.5f};
    const float s3[3] = {0.f, 0.86602540378443864676f, -0.86602540378443864676f};

    float base[3][3];
#pragma unroll
    for (int y = 0; y < 3; ++y)
#pragma unroll
        for (int x = 0; x < 3; ++x) {
            float sum = 0.f;
#pragma unroll
            for (int ky = 0; ky < 3; ++ky)
#pragma unroll
                for (int kx = 0; kx < 3; ++kx) {
                    float rf, mf;
                    if (kx < 2) {
                        rf = re[ky][kx];
                        mf = im[ky][kx];
                    } else {
                        int kys = (3 - ky) % 3;
                        rf = re[kys][1];
                        mf = -im[kys][1];
                    }
                    int m = (ky * y + kx * x) % 3;
                    sum += rf * c3[m] - mf * s3[m];
                }
            base[y][x] = sum * (1.f / 9.f);
        }

    const float scales[4] = {1.f, 1.25f, 1.5625f, 1.953125f};
    const float coords[3] = {-2.f / 3.f, 0.f, 2.f / 3.f};

    float acc[3][3] = {{0.f, 0.f, 0.f}, {0.f, 0.f, 0.f}, {0.f, 0.f, 0.f}};

    for (int t = 0; t < 32; ++t) {
        int r = t >> 2, si = t & 3;
        float th = (float)r * 0.78539816339744830961f;
        float sc = scales[si];
        float c = cosf(th) * sc;
        float s = sinf(th) * sc;
#pragma unroll
        for (int p = 0; p < 3; ++p) {
#pragma unroll
            for (int q = 0; q < 3; ++q) {
                float gxo = coords[q], gyo = coords[p];
                float gx = c * gxo - s * gyo;
                float gy = s * gxo + c * gyo;
                float ix = ((gx + 1.f) * 3.f - 1.f) * 0.5f;
                float iy = ((gy + 1.f) * 3.f - 1.f) * 0.5f;
                float fx0 = floorf(ix), fy0 = floorf(iy);
                int x0 = (int)fx0, y0 = (int)fy0;
                int x1 = x0 + 1, y1 = y0 + 1;
                float wx1 = ix - fx0, wy1 = iy - fy0;
                float wx0 = 1.f - wx1, wy0 = 1.f - wy1;

                float v = 0.f;
                {
                    int yc = min(max(y0, 0), 2), xc = min(max(x0, 0), 2);
                    bool ok = (x0 >= 0) & (x0 < 3) & (y0 >= 0) & (y0 < 3);
                    v += (ok ? base[yc][xc] : 0.f) * (wy0 * wx0);
                }
                {
                    int yc = min(max(y0, 0), 2), xc = min(max(x1, 0), 2);
                    bool ok = (x1 >= 0) & (x1 < 3) & (y0 >= 0) & (y0 < 3);
                    v += (ok ? base[yc][xc] : 0.f) * (wy0 * wx1);
                }
                {
                    int yc = min(max(y1, 0), 2), xc = min(max(x0, 0), 2);
                    bool ok = (x0 >= 0) & (x0 < 3) & (y1 >= 0) & (y1 < 3);
                    v += (ok ? base[yc][xc] : 0.f) * (wy1 * wx0);
                }
                {
                    int yc = min(max(y1, 0), 2), xc = min(max(x1, 0), 2);
                    bool ok = (x1 >= 0) & (x1 < 3) & (y1 >= 0) & (y1 < 3);
                    v += (ok ? base[yc][xc] : 0.f) * (wy1 * wx1);
                }
                acc[p][q] += v;
            }
        }
    }

    // wbuf[(tap*2+hl)*1024 + o*32 + i]: A rows = o, k = i.
#pragma unroll
    for (int p = 0; p < 3; ++p)
#pragma unroll
        for (int q = 0; q < 3; ++q) {
            int t = p * 3 + q;
            float w = acc[p][q] * (1.f / 32.f);
            unsigned short wh = f2bf(w);
            unsigned short wl = f2bf(w - bf2f(wh));
            size_t b = (size_t)(t * 2) * 1024 + o * 32 + i;
            wbuf[b] = wh;
            wbuf[b + 1024] = wl;
        }
}

// ---------------- conv: 8x32 tile, 4 waves, 32x32x16 MFMA ----------------
#define TLH 8
#define TLW 32
#define LCOLS 34
#define LROWS 10
#define NPX 340  // 10*34 halo pixels, 64 B each (32 ch bf16)

// read-conflict-free bank swizzle: any 8 consecutive px cover all 8 16B phases
__device__ __forceinline__ unsigned lds_byte(int px, int c) {
    return ((unsigned)px << 6) + ((((unsigned)(px >> 1) & 3u) ^ (unsigned)c) << 4);
}

__global__ __launch_bounds__(256, 8) void conv_mfma(const float* __restrict__ x,
                                                    const unsigned short* __restrict__ wbuf,
                                                    float* __restrict__ out)
{
    __shared__ unsigned slds[NPX * 16];  // 21760 B -> 7 blocks/CU

    // flat grid 8192 = 16x * 64y * 8n; bijective XCD swizzle, y-fastest:
    // XCD k gets ids [k*1024, (k+1)*1024) = exactly batch image k.
    const int lin = blockIdx.x;
    const int s = (lin & 7) * 1024 + (lin >> 3);
    const int n = s >> 10;
    const int rem = s & 1023;
    const int y0t = (rem & 63) * TLH;
    const int x0t = (rem >> 6) * TLW;

    const int tid = threadIdx.x;
    const float* xn = x + ((size_t)n << 23);

    // ---- stage: 320 vector units (c-octet,row,x-quad) + 80 scalar halo units ----
    for (int t = tid; t < 320 + 80; t += 256) {
        if (t < 320) {
            int c = t / 80;              // channel octet
            int rem2 = t - c * 80;
            int row = rem2 >> 3;         // 0..9
            int q = rem2 & 7;
            int gy = y0t + row - 1;
            int gx0 = x0t + (q << 2);    // 16B-aligned
            float v[8][4];
            if ((unsigned)gy < 512u) {
                const float* src = xn + (((size_t)c << 3) << 18) + ((gy << 9) + gx0);
#pragma unroll
                for (int cc = 0; cc < 8; ++cc) {
                    f32x4v ld = *(const f32x4v*)(src + ((size_t)cc << 18));
#pragma unroll
                    for (int j = 0; j < 4; ++j) v[cc][j] = ld[j];
                }
            } else {
#pragma unroll
                for (int cc = 0; cc < 8; ++cc)
#pragma unroll
                    for (int j = 0; j < 4; ++j) v[cc][j] = 0.f;
            }
            int px0 = row * LCOLS + 1 + (q << 2);
#pragma unroll
            for (int j = 0; j < 4; ++j) {
                u32x4 d;
#pragma unroll
                for (int p = 0; p < 4; ++p)
                    d[p] = (unsigned)f2bf(v[2 * p][j]) | ((unsigned)f2bf(v[2 * p + 1][j]) << 16);
                *(u32x4*)((char*)slds + lds_byte(px0 + j, c)) = d;
            }
        } else {
            int sidx = t - 320;
            int c = sidx / 20;
            int rem2 = sidx - c * 20;
            int row = rem2 >> 1;         // 0..9
            int side = rem2 & 1;
            int gy = y0t + row - 1;
            int gx = x0t + (side ? 32 : -1);
            bool ok = ((unsigned)gy < 512u) & ((unsigned)gx < 512u);
            u32x4 d;
#pragma unroll
            for (int p = 0; p < 4; ++p) {
                float f0 = 0.f, f1 = 0.f;
                if (ok) {
                    const float* srcp = xn + (((size_t)(c * 8 + 2 * p)) << 18) + ((gy << 9) + gx);
                    f0 = srcp[0];
                    f1 = srcp[(size_t)1 << 18];
                }
                d[p] = (unsigned)f2bf(f0) | ((unsigned)f2bf(f1) << 16);
            }
            int px = row * LCOLS + (side ? 33 : 0);
            *(u32x4*)((char*)slds + lds_byte(px, c)) = d;
        }
    }
    __syncthreads();

    // ---- MFMA: wave wv owns out rows {2wv, 2wv+1}, all 32 o ----
    const int lane = tid & 63;
    const int wv = tid >> 6;    // 0..3
    const int pxl = lane & 31;  // B col = pixel
    const int kh = lane >> 5;   // B k-half
    const int r0 = wv << 1;

    f32x16 acc[2];
#pragma unroll
    for (int f = 0; f < 2; ++f)
#pragma unroll
        for (int r = 0; r < 16; ++r) acc[f][r] = 0.f;

#pragma unroll 1
    for (int dy = 0; dy < 3; ++dy) {
        // A-frags for this dy: lane holds row o=pxl, k = kh*8 + j of K=16
        bf16x8 A[3][2][2];  // [dx][hl][kstep]
#pragma unroll
        for (int dx = 0; dx < 3; ++dx)
#pragma unroll
            for (int hl = 0; hl < 2; ++hl)
#pragma unroll
                for (int ks = 0; ks < 2; ++ks) {
                    int tap = dy * 3 + dx;
                    A[dx][hl][ks] = *(const bf16x8*)(wbuf + (size_t)(tap * 2 + hl) * 1024 +
                                                     pxl * 32 + ks * 16 + kh * 8);
                }
#pragma unroll
        for (int f = 0; f < 2; ++f) {
            int lrow = r0 + f + dy;  // LDS row (0 = global y0t-1)
#pragma unroll
            for (int dx = 0; dx < 3; ++dx) {
                int px = lrow * LCOLS + dx + pxl;
#pragma unroll
                for (int ks = 0; ks < 2; ++ks) {
                    bf16x8 b = *(const bf16x8*)((const char*)slds + lds_byte(px, ks * 2 + kh));
                    acc[f] = __builtin_amdgcn_mfma_f32_32x32x16_bf16(A[dx][0][ks], b, acc[f], 0, 0, 0);
                    acc[f] = __builtin_amdgcn_mfma_f32_32x32x16_bf16(A[dx][1][ks], b, acc[f], 0, 0, 0);
                }
            }
        }
    }

    // ---- epilogue: C/D col=lane&31 (px), row=(reg&3)+8*(reg>>2)+4*(lane>>5) (o)
#pragma unroll
    for (int f = 0; f < 2; ++f) {
        int gy = y0t + r0 + f;
#pragma unroll
        for (int reg = 0; reg < 16; ++reg) {
            int o = (reg & 3) + 8 * (reg >> 2) + 4 * kh;
            size_t idx = ((size_t)(n * 32 + o) << 18) + (size_t)(gy << 9) + x0t + pxl;
            __builtin_nontemporal_store(acc[f][reg], &out[idx]);
        }
    }
}

extern "C" void kernel_launch(void* const* d_in, const int* in_sizes, int n_in,
                              void* d_out, int out_size, void* d_ws, size_t ws_size,
                              hipStream_t stream) {
    const float* x = (const float*)d_in[0];
    const float* fw = (const float*)d_in[1];
    float* out = (float*)d_out;
    unsigned short* wbuf = (unsigned short*)d_ws;  // 18*1024 bf16 = 36864 B

    prep_kernel<<<dim3(4), 256, 0, stream>>>(fw, wbuf);
    conv_mfma<<<dim3(8192), 256, 0, stream>>>(x, wbuf, out);
}